// Round 13
// baseline (272.794 us; speedup 1.0000x reference)
//
#include <hip/hip_runtime.h>
#include <math.h>

// SimpleGCN: h1 = relu(GCN(x,W1,b1)); h2 = relu(GCN(h1,W2,b2));
// g = mean(h2, axis=0); out = (g@Wr + br) -> 128 fp32.
// GCN(x,W,b)[d] = dinv[d]*( sum_{s in N(d)} y[s] + y[d] ) + b,
//   y = dinv * (x@W), dinv[i] = (1+indeg[i])^-0.5.
//
// R12 post-mortem: agg FETCH halved (bf16 worked) but dur stuck ~51us ->
// dependency-latency bound (offsets->csr->gather chain, ~5 loads/wave life).
// R13: 2-node software pipelining per wave — nodes 2b,2b+1 interleaved
// SEQUENTIALLY (loop bounds stay wave-uniform; R9 showed lane-splitting
// nodes is fatal). 2x loads in flight, half the waves; fused epilogue
// shares each Ws LDS read across both nodes. CH 4096->2048 (391 blocks).

#define CH 2048    // edges per chunk-block in hist/scatter
#define MAXNB 1024 // NB = ceil(n/64) <= 1024 (n <= 65536)

__device__ __forceinline__ float bf2f(unsigned short u) {
    return __uint_as_float(((unsigned)u) << 16);
}
__device__ __forceinline__ unsigned short f2bf(float x) {
    unsigned b = __float_as_uint(x);
    return (unsigned short)((b + 0x7FFF + ((b >> 16) & 1)) >> 16);  // RNE
}

__global__ __launch_bounds__(256) void k_bucket_hist(const int* __restrict__ dst,
                                                     int* __restrict__ histmat,
                                                     int E, int NB) {
    __shared__ int ih[MAXNB];
    int t = threadIdx.x;
    for (int k = t; k < NB; k += 256) ih[k] = 0;
    __syncthreads();
    int base = blockIdx.x * CH;
    for (int i = 0; i < CH; i += 256) {
        int e = base + i + t;
        if (e < E) atomicAdd(&ih[dst[e] >> 6], 1);
    }
    __syncthreads();
    for (int k = t; k < NB; k += 256) histmat[(size_t)blockIdx.x * NB + k] = ih[k];
}

// ONE block, 1024 threads (thread = bucket, NB<=1024): per-bucket exclusive
// prefix over chunks (in-place, coalesced, unroll-8), then in-LDS scan of
// bucket totals -> bstart. Also zeroes g.
__global__ __launch_bounds__(1024) void k_scan(int* __restrict__ histmat,
                                               int* __restrict__ bstart,
                                               int* __restrict__ offsets,
                                               float* __restrict__ g,
                                               int NB, int nch, int E, int n) {
    __shared__ int sc[1024];
    int t = threadIdx.x;
    int run = 0;
    if (t < NB) {
        int b = 0;
        for (; b + 8 <= nch; b += 8) {
            int v[8];
#pragma unroll
            for (int u = 0; u < 8; u++) v[u] = histmat[(size_t)(b + u) * NB + t];
#pragma unroll
            for (int u = 0; u < 8; u++) {
                int x = v[u];
                histmat[(size_t)(b + u) * NB + t] = run;
                run += x;
            }
        }
        for (; b < nch; b++) {
            int x = histmat[(size_t)b * NB + t];
            histmat[(size_t)b * NB + t] = run;
            run += x;
        }
    }
    sc[t] = (t < NB) ? run : 0;
    __syncthreads();
    for (int off = 1; off < 1024; off <<= 1) {
        int x = (t >= off) ? sc[t - off] : 0;
        __syncthreads();
        sc[t] += x;
        __syncthreads();
    }
    if (t < NB) bstart[t] = sc[t] - run;  // exclusive
    if (t == 0) { bstart[NB] = E; offsets[n] = E; }
    if (t < 64) g[t] = 0.f;
}

__global__ __launch_bounds__(256) void k_bucket_scatter(const int* __restrict__ src,
                                                        const int* __restrict__ dst,
                                                        const int* __restrict__ histmat,
                                                        const int* __restrict__ bstart,
                                                        int* __restrict__ staged,
                                                        int E, int NB) {
    __shared__ int cur[MAXNB];
    int t = threadIdx.x;
    for (int k = t; k < NB; k += 256)
        cur[k] = bstart[k] + histmat[(size_t)blockIdx.x * NB + k];
    __syncthreads();
    int base = blockIdx.x * CH;
    for (int i = 0; i < CH; i += 256) {
        int e = base + i + t;
        if (e < E) {
            int d = dst[e];
            int pos = atomicAdd(&cur[d >> 6], 1);
            staged[pos] = (src[e] << 6) | (d & 63);  // n<=65536 -> fits
        }
    }
}

// one block per bucket: counting-sort staged run into node-granular ushort
// CSR; emit per-node offsets + dinv.
__global__ __launch_bounds__(256) void k_local_sort(const int* __restrict__ staged,
                                                    const int* __restrict__ bstart,
                                                    unsigned short* __restrict__ csr,
                                                    int* __restrict__ offsets,
                                                    float* __restrict__ dinv, int n) {
    __shared__ int cnt[64];
    __shared__ int pos[64];
    __shared__ int cur[64];
    int t = threadIdx.x;
    if (t < 64) cnt[t] = 0;
    __syncthreads();
    int k = blockIdx.x;
    int beg = bstart[k], end = bstart[k + 1];
    for (int e = beg + t; e < end; e += 256) atomicAdd(&cnt[staged[e] & 63], 1);
    __syncthreads();
    if (t == 0) {
        int run = 0;
        for (int i = 0; i < 64; i++) { pos[i] = run; run += cnt[i]; }
    }
    __syncthreads();
    if (t < 64) {
        cur[t] = pos[t];
        int node = k * 64 + t;
        if (node < n) {
            offsets[node] = beg + pos[t];
            dinv[node] = 1.0f / sqrtf((float)(cnt[t] + 1));  // + self-loop
        }
    }
    __syncthreads();
    for (int e = beg + t; e < end; e += 256) {
        int pk = staged[e];
        int p = atomicAdd(&cur[pk & 63], 1);
        csr[beg + p] = (unsigned short)(pk >> 6);
    }
}

// y1[i,:] = dinv[i] * (X[i,:] @ W) stored as bf16 rows (128B = 1 line).
__global__ __launch_bounds__(256) void k_gemm_scale(const float* __restrict__ X,
                                                    const float* __restrict__ W,
                                                    const float* __restrict__ dinv,
                                                    unsigned short* __restrict__ Y, int n) {
    __shared__ float Ws[64 * 64];
    __shared__ float xs[16][64];
    int t = threadIdx.x, w = t >> 6, f = t & 63;
    const float4* W4 = (const float4*)W;
    float4* Ws4 = (float4*)Ws;
#pragma unroll
    for (int j = 0; j < 4; j++) Ws4[t + 256 * j] = W4[t + 256 * j];
    int r0 = blockIdx.x * 16;
#pragma unroll
    for (int i = 0; i < 4; i++) {
        int r = r0 + w * 4 + i;
        xs[w * 4 + i][f] = (r < n) ? X[(size_t)r * 64 + f] : 0.f;
    }
    __syncthreads();
    float acc[4] = {0.f, 0.f, 0.f, 0.f};
#pragma unroll 8
    for (int k = 0; k < 64; k++) {
        float wv = Ws[k * 64 + f];
#pragma unroll
        for (int i = 0; i < 4; i++) acc[i] += xs[w * 4 + i][k] * wv;
    }
#pragma unroll
    for (int i = 0; i < 4; i++) {
        int r = r0 + w * 4 + i;
        if (r < n) Y[(size_t)r * 64 + f] = f2bf(dinv[r] * acc[i]);
    }
}

__device__ __forceinline__ void xorred(float4& a, int m) {
    a.x += __shfl_xor(a.x, m);
    a.y += __shfl_xor(a.y, m);
    a.z += __shfl_xor(a.z, m);
    a.w += __shfl_xor(a.w, m);
}

// 2-node gather core: wave handles nodes nA=base, nB=base+1 sequentially
// interleaved. lane=(q,c): q=lane>>4 edge slot, c=lane&15 (row as 16
// ushort4). Both nodes' loads issue per sweep -> ~2x loads in flight.
// Loop condition wave-"uniform enough" (exec-mask only). After xor reduce
// ALL lanes hold each node's full quarter h.
#define GATHER2(Y4, offsets, csr, nA, nB, vA, vB, accA, accB)                 \
    {                                                                         \
        int begA = 0, endA = 0, begB = 0, endB = 0;                           \
        if (vA) { begA = offsets[nA]; endA = offsets[nA + 1]; }               \
        if (vB) { begB = offsets[nB]; endB = offsets[nB + 1]; }               \
        if (vA && q == 0) {                                                   \
            ushort4 u = Y4[(size_t)nA * 16 + c];                              \
            accA = make_float4(bf2f(u.x), bf2f(u.y), bf2f(u.z), bf2f(u.w));   \
        }                                                                     \
        if (vB && q == 0) {                                                   \
            ushort4 u = Y4[(size_t)nB * 16 + c];                              \
            accB = make_float4(bf2f(u.x), bf2f(u.y), bf2f(u.z), bf2f(u.w));   \
        }                                                                     \
        int jA = begA + q, jB = begB + q;                                     \
        while (jA < endA || jB < endB) {                                      \
            _Pragma("unroll")                                                 \
            for (int u = 0; u < 4; u++) {                                     \
                int ja = jA + 4 * u;                                          \
                if (ja < endA) {                                              \
                    int s = csr[ja];                                          \
                    ushort4 v = Y4[(size_t)s * 16 + c];                       \
                    accA.x += bf2f(v.x); accA.y += bf2f(v.y);                 \
                    accA.z += bf2f(v.z); accA.w += bf2f(v.w);                 \
                }                                                             \
                int jb = jB + 4 * u;                                          \
                if (jb < endB) {                                              \
                    int s = csr[jb];                                          \
                    ushort4 v = Y4[(size_t)s * 16 + c];                       \
                    accB.x += bf2f(v.x); accB.y += bf2f(v.y);                 \
                    accB.z += bf2f(v.z); accB.w += bf2f(v.w);                 \
                }                                                             \
            }                                                                 \
            jA += 16; jB += 16;                                               \
        }                                                                     \
        xorred(accA, 16); xorred(accA, 32);                                   \
        xorred(accB, 16); xorred(accB, 32);                                   \
    }

// Layer-1 aggregate (2 nodes/wave) + fused GEMM2 epilogue (one Ws read
// feeds both nodes' FMAs). Block = 4 waves = 8 nodes.
__global__ __launch_bounds__(256) void k_agg_fuse(const unsigned short* __restrict__ Y,
                                                  const float* __restrict__ dinv,
                                                  const float* __restrict__ bias,
                                                  const int* __restrict__ offsets,
                                                  const unsigned short* __restrict__ csr,
                                                  const float* __restrict__ W2,
                                                  unsigned short* __restrict__ Yout, int n) {
    __shared__ float Ws[64 * 64];   // 16 KB
    __shared__ float hs[4][2][64];  // 2 KB
    const ushort4* Y4 = (const ushort4*)Y;
    int t = threadIdx.x, w = t >> 6, l = t & 63;
    int q = l >> 4, c = l & 15;
    {
        const float4* W4 = (const float4*)W2;
        float4* Ws4 = (float4*)Ws;
#pragma unroll
        for (int j = 0; j < 4; j++) Ws4[t + 256 * j] = W4[t + 256 * j];
    }
    int nA = (blockIdx.x * 4 + w) * 2;
    int nB = nA + 1;
    bool vA = nA < n, vB = nB < n;
    float4 accA = make_float4(0.f, 0.f, 0.f, 0.f);
    float4 accB = make_float4(0.f, 0.f, 0.f, 0.f);
    GATHER2(Y4, offsets, csr, nA, nB, vA, vB, accA, accB);
    float dvA = vA ? dinv[nA] : 0.f;
    float dvB = vB ? dinv[nB] : 0.f;
    float4 b4 = ((const float4*)bias)[c];
    float4 hA, hB;
    hA.x = fmaxf(dvA * accA.x + b4.x, 0.f);
    hA.y = fmaxf(dvA * accA.y + b4.y, 0.f);
    hA.z = fmaxf(dvA * accA.z + b4.z, 0.f);
    hA.w = fmaxf(dvA * accA.w + b4.w, 0.f);
    hB.x = fmaxf(dvB * accB.x + b4.x, 0.f);
    hB.y = fmaxf(dvB * accB.y + b4.y, 0.f);
    hB.z = fmaxf(dvB * accB.z + b4.z, 0.f);
    hB.w = fmaxf(dvB * accB.w + b4.w, 0.f);
    if (q == 0) {
        ((float4*)hs[w][0])[c] = hA;
        ((float4*)hs[w][1])[c] = hB;
    }
    __syncthreads();
    float a2A = 0.f, a2B = 0.f;
#pragma unroll
    for (int m = 0; m < 16; m++) {
        float4 xA = ((const float4*)hs[w][0])[m];
        float4 xB = ((const float4*)hs[w][1])[m];
        float w0 = Ws[(4 * m + 0) * 64 + l], w1 = Ws[(4 * m + 1) * 64 + l];
        float w2 = Ws[(4 * m + 2) * 64 + l], w3 = Ws[(4 * m + 3) * 64 + l];
        a2A += xA.x * w0 + xA.y * w1 + xA.z * w2 + xA.w * w3;
        a2B += xB.x * w0 + xB.y * w1 + xB.z * w2 + xB.w * w3;
    }
    if (vA) Yout[(size_t)nA * 64 + l] = f2bf(dvA * a2A);
    if (vB) Yout[(size_t)nB * 64 + l] = f2bf(dvB * a2B);
}

// Layer-2 aggregate (2 nodes/wave) + per-block partial mean rows.
__global__ __launch_bounds__(256) void k_agg_pool(const unsigned short* __restrict__ Y,
                                                  const float* __restrict__ dinv,
                                                  const float* __restrict__ bias,
                                                  const int* __restrict__ offsets,
                                                  const unsigned short* __restrict__ csr,
                                                  float* __restrict__ pbuf, int n) {
    __shared__ float4 sm4[4][16];
    const ushort4* Y4 = (const ushort4*)Y;
    int t = threadIdx.x, w = t >> 6, l = t & 63;
    int q = l >> 4, c = l & 15;
    int nA = (blockIdx.x * 4 + w) * 2;
    int nB = nA + 1;
    bool vA = nA < n, vB = nB < n;
    float4 accA = make_float4(0.f, 0.f, 0.f, 0.f);
    float4 accB = make_float4(0.f, 0.f, 0.f, 0.f);
    GATHER2(Y4, offsets, csr, nA, nB, vA, vB, accA, accB);
    float dvA = vA ? dinv[nA] : 0.f;
    float dvB = vB ? dinv[nB] : 0.f;
    float4 b4 = ((const float4*)bias)[c];
    float4 s;
    s.x = (vA ? fmaxf(dvA * accA.x + b4.x, 0.f) : 0.f)
        + (vB ? fmaxf(dvB * accB.x + b4.x, 0.f) : 0.f);
    s.y = (vA ? fmaxf(dvA * accA.y + b4.y, 0.f) : 0.f)
        + (vB ? fmaxf(dvB * accB.y + b4.y, 0.f) : 0.f);
    s.z = (vA ? fmaxf(dvA * accA.z + b4.z, 0.f) : 0.f)
        + (vB ? fmaxf(dvB * accB.z + b4.z, 0.f) : 0.f);
    s.w = (vA ? fmaxf(dvA * accA.w + b4.w, 0.f) : 0.f)
        + (vB ? fmaxf(dvB * accB.w + b4.w, 0.f) : 0.f);
    if (q == 0) sm4[w][c] = s;
    __syncthreads();
    if (t < 16) {
        float4 a = sm4[0][t], b = sm4[1][t], d = sm4[2][t], e = sm4[3][t];
        float4 o;
        o.x = (a.x + b.x) + (d.x + e.x);
        o.y = (a.y + b.y) + (d.y + e.y);
        o.z = (a.z + b.z) + (d.z + e.z);
        o.w = (a.w + b.w) + (d.w + e.w);
        ((float4*)pbuf)[(size_t)blockIdx.x * 16 + t] = o;
    }
}

__global__ void k_mean_final(const float* __restrict__ pbuf, float* __restrict__ g,
                             int nrows) {
    __shared__ float part[256];
    int t = threadIdx.x, w = t >> 6, f = t & 63;
    float local = 0.f;
    for (int r = blockIdx.x * 4 + w; r < nrows; r += gridDim.x * 4)
        local += pbuf[(size_t)r * 64 + f];
    part[t] = local;
    __syncthreads();
    if (w == 0) {
        float tot = part[f] + part[64 + f] + part[128 + f] + part[192 + f];
        atomicAdd(&g[f], tot);
    }
}

__global__ void k_readout(const float* __restrict__ g, const float* __restrict__ Wr,
                          const float* __restrict__ br, float* __restrict__ out,
                          float invn) {
    __shared__ float gl[64];
    int t = threadIdx.x;
    if (t < 64) gl[t] = g[t] * invn;
    __syncthreads();
    float acc = br[t];
#pragma unroll
    for (int k = 0; k < 64; k++) acc += gl[k] * Wr[k * 128 + t];
    out[t] = acc;
}

extern "C" void kernel_launch(void* const* d_in, const int* in_sizes, int n_in,
                              void* d_out, int out_size, void* d_ws, size_t ws_size,
                              hipStream_t stream) {
    const float* x  = (const float*)d_in[0];
    const int*   ei = (const int*)d_in[1];   // int32 on device (JAX x64 off)
    const float* W1 = (const float*)d_in[2];
    const float* b1 = (const float*)d_in[3];
    const float* W2 = (const float*)d_in[4];
    const float* b2 = (const float*)d_in[5];
    const float* Wr = (const float*)d_in[6];
    const float* br = (const float*)d_in[7];
    float* out = (float*)d_out;

    int n = in_sizes[0] / 64;   // 50000
    int E = in_sizes[1] / 2;    // 800000
    const int* src = ei;
    const int* dst = ei + E;

    int NB  = (n + 63) / 64;       // 782 buckets of 64 nodes
    int nch = (E + CH - 1) / CH;   // 391 chunks

    // workspace layout (~23 MB)
    char* p = (char*)d_ws;
    unsigned short* y1 = (unsigned short*)p; p += (size_t)n * 64 * sizeof(unsigned short);
    unsigned short* y2 = (unsigned short*)p; p += (size_t)n * 64 * sizeof(unsigned short);
    float* pbuf = (float*)p;   p += (size_t)((n + 7) / 8) * 64 * sizeof(float);
    float* dinv = (float*)p;   p += (size_t)n * sizeof(float);
    float* g = (float*)p;      p += 64 * sizeof(float);
    int* staged = (int*)p;     p += (size_t)E * sizeof(int);
    int* offsets = (int*)p;    p += (size_t)(n + 1) * sizeof(int);
    int* histmat = (int*)p;    p += (size_t)nch * NB * sizeof(int);
    int* bstart = (int*)p;     p += (size_t)(NB + 1) * sizeof(int);
    unsigned short* csr = (unsigned short*)p; p += (size_t)E * sizeof(unsigned short);

    k_bucket_hist<<<nch, 256, 0, stream>>>(dst, histmat, E, NB);
    k_scan<<<1, 1024, 0, stream>>>(histmat, bstart, offsets, g, NB, nch, E, n);
    k_bucket_scatter<<<nch, 256, 0, stream>>>(src, dst, histmat, bstart, staged, E, NB);
    k_local_sort<<<NB, 256, 0, stream>>>(staged, bstart, csr, offsets, dinv, n);

    int gb2 = (n + 7) / 8;  // 6250 aggregate blocks (2 nodes per wave)
    k_gemm_scale<<<(n + 15) / 16, 256, 0, stream>>>(x, W1, dinv, y1, n);
    k_agg_fuse<<<gb2, 256, 0, stream>>>(y1, dinv, b1, offsets, csr, W2, y2, n);
    k_agg_pool<<<gb2, 256, 0, stream>>>(y2, dinv, b2, offsets, csr, pbuf, n);

    k_mean_final<<<64, 256, 0, stream>>>(pbuf, g, gb2);
    k_readout<<<1, 128, 0, stream>>>(g, Wr, br, out, 1.0f / (float)n);
}

// Round 14
// 230.413 us; speedup vs baseline: 1.1839x; 1.1839x over previous
//
#include <hip/hip_runtime.h>
#include <math.h>

// SimpleGCN: h1 = relu(GCN(x,W1,b1)); h2 = relu(GCN(h1,W2,b2));
// g = mean(h2, axis=0); out = (g@Wr + br) -> 128 fp32.
// GCN(x,W,b)[d] = dinv[d]*( sum_{s in N(d)} y[s] + y[d] ) + b,
//   y = dinv * (x@W), dinv[i] = (1+indeg[i])^-0.5.
//
// R13 post-mortem: 2-node pipelining blew VGPR 16->76, occupancy 68->29%
// — TLP beats register-bought ILP here. R14 = R12 (best, 229.9us) +
// (a) readfirstlane-scalarized gather bounds (s_cbranch loops, less VALU),
// (b) offsets/dinv/self-row loads issued before the W2 LDS staging so their
// latency overlaps. Structure unchanged: 9 dispatches, bf16 rows, ushort
// CSR, wave-per-node gather, gemm2 fused into agg1, pooled mean in agg2.

#define CH 4096    // edges per chunk-block in hist/scatter
#define MAXNB 1024 // NB = ceil(n/64) <= 1024 (n <= 65536)

__device__ __forceinline__ float bf2f(unsigned short u) {
    return __uint_as_float(((unsigned)u) << 16);
}
__device__ __forceinline__ unsigned short f2bf(float x) {
    unsigned b = __float_as_uint(x);
    return (unsigned short)((b + 0x7FFF + ((b >> 16) & 1)) >> 16);  // RNE
}

__global__ __launch_bounds__(256) void k_bucket_hist(const int* __restrict__ dst,
                                                     int* __restrict__ histmat,
                                                     int E, int NB) {
    __shared__ int ih[MAXNB];
    int t = threadIdx.x;
    for (int k = t; k < NB; k += 256) ih[k] = 0;
    __syncthreads();
    int base = blockIdx.x * CH;
    for (int i = 0; i < CH; i += 256) {
        int e = base + i + t;
        if (e < E) atomicAdd(&ih[dst[e] >> 6], 1);
    }
    __syncthreads();
    for (int k = t; k < NB; k += 256) histmat[(size_t)blockIdx.x * NB + k] = ih[k];
}

// ONE block, 1024 threads (thread = bucket, NB<=1024): per-bucket exclusive
// prefix over chunks (in-place, coalesced, unroll-8), then in-LDS scan of
// bucket totals -> bstart. Also zeroes g.
__global__ __launch_bounds__(1024) void k_scan(int* __restrict__ histmat,
                                               int* __restrict__ bstart,
                                               int* __restrict__ offsets,
                                               float* __restrict__ g,
                                               int NB, int nch, int E, int n) {
    __shared__ int sc[1024];
    int t = threadIdx.x;
    int run = 0;
    if (t < NB) {
        int b = 0;
        for (; b + 8 <= nch; b += 8) {
            int v[8];
#pragma unroll
            for (int u = 0; u < 8; u++) v[u] = histmat[(size_t)(b + u) * NB + t];
#pragma unroll
            for (int u = 0; u < 8; u++) {
                int x = v[u];
                histmat[(size_t)(b + u) * NB + t] = run;
                run += x;
            }
        }
        for (; b < nch; b++) {
            int x = histmat[(size_t)b * NB + t];
            histmat[(size_t)b * NB + t] = run;
            run += x;
        }
    }
    sc[t] = (t < NB) ? run : 0;
    __syncthreads();
    for (int off = 1; off < 1024; off <<= 1) {
        int x = (t >= off) ? sc[t - off] : 0;
        __syncthreads();
        sc[t] += x;
        __syncthreads();
    }
    if (t < NB) bstart[t] = sc[t] - run;  // exclusive
    if (t == 0) { bstart[NB] = E; offsets[n] = E; }
    if (t < 64) g[t] = 0.f;
}

__global__ __launch_bounds__(256) void k_bucket_scatter(const int* __restrict__ src,
                                                        const int* __restrict__ dst,
                                                        const int* __restrict__ histmat,
                                                        const int* __restrict__ bstart,
                                                        int* __restrict__ staged,
                                                        int E, int NB) {
    __shared__ int cur[MAXNB];
    int t = threadIdx.x;
    for (int k = t; k < NB; k += 256)
        cur[k] = bstart[k] + histmat[(size_t)blockIdx.x * NB + k];
    __syncthreads();
    int base = blockIdx.x * CH;
    for (int i = 0; i < CH; i += 256) {
        int e = base + i + t;
        if (e < E) {
            int d = dst[e];
            int pos = atomicAdd(&cur[d >> 6], 1);
            staged[pos] = (src[e] << 6) | (d & 63);  // n<=65536 -> fits
        }
    }
}

// one block per bucket: counting-sort staged run into node-granular ushort
// CSR; emit per-node offsets + dinv.
__global__ __launch_bounds__(256) void k_local_sort(const int* __restrict__ staged,
                                                    const int* __restrict__ bstart,
                                                    unsigned short* __restrict__ csr,
                                                    int* __restrict__ offsets,
                                                    float* __restrict__ dinv, int n) {
    __shared__ int cnt[64];
    __shared__ int pos[64];
    __shared__ int cur[64];
    int t = threadIdx.x;
    if (t < 64) cnt[t] = 0;
    __syncthreads();
    int k = blockIdx.x;
    int beg = bstart[k], end = bstart[k + 1];
    for (int e = beg + t; e < end; e += 256) atomicAdd(&cnt[staged[e] & 63], 1);
    __syncthreads();
    if (t == 0) {
        int run = 0;
        for (int i = 0; i < 64; i++) { pos[i] = run; run += cnt[i]; }
    }
    __syncthreads();
    if (t < 64) {
        cur[t] = pos[t];
        int node = k * 64 + t;
        if (node < n) {
            offsets[node] = beg + pos[t];
            dinv[node] = 1.0f / sqrtf((float)(cnt[t] + 1));  // + self-loop
        }
    }
    __syncthreads();
    for (int e = beg + t; e < end; e += 256) {
        int pk = staged[e];
        int p = atomicAdd(&cur[pk & 63], 1);
        csr[beg + p] = (unsigned short)(pk >> 6);
    }
}

// y1[i,:] = dinv[i] * (X[i,:] @ W) stored as bf16 rows (128B = 1 line).
__global__ __launch_bounds__(256) void k_gemm_scale(const float* __restrict__ X,
                                                    const float* __restrict__ W,
                                                    const float* __restrict__ dinv,
                                                    unsigned short* __restrict__ Y, int n) {
    __shared__ float Ws[64 * 64];
    __shared__ float xs[16][64];
    int t = threadIdx.x, w = t >> 6, f = t & 63;
    const float4* W4 = (const float4*)W;
    float4* Ws4 = (float4*)Ws;
#pragma unroll
    for (int j = 0; j < 4; j++) Ws4[t + 256 * j] = W4[t + 256 * j];
    int r0 = blockIdx.x * 16;
#pragma unroll
    for (int i = 0; i < 4; i++) {
        int r = r0 + w * 4 + i;
        xs[w * 4 + i][f] = (r < n) ? X[(size_t)r * 64 + f] : 0.f;
    }
    __syncthreads();
    float acc[4] = {0.f, 0.f, 0.f, 0.f};
#pragma unroll 8
    for (int k = 0; k < 64; k++) {
        float wv = Ws[k * 64 + f];
#pragma unroll
        for (int i = 0; i < 4; i++) acc[i] += xs[w * 4 + i][k] * wv;
    }
#pragma unroll
    for (int i = 0; i < 4; i++) {
        int r = r0 + w * 4 + i;
        if (r < n) Y[(size_t)r * 64 + f] = f2bf(dinv[r] * acc[i]);
    }
}

// Layer-1 aggregate + fused GEMM2 (R12 structure). One wave per node,
// lane=(q,c): q=lane>>4 edge slot, c=lane&15 (row as 16 x ushort4).
// Gather bounds pinned to SGPRs via readfirstlane (scalar loop control).
// Gather-head loads issued BEFORE the 16KB W2 staging so latency overlaps.
__global__ __launch_bounds__(256) void k_agg_fuse(const unsigned short* __restrict__ Y,
                                                  const float* __restrict__ dinv,
                                                  const float* __restrict__ bias,
                                                  const int* __restrict__ offsets,
                                                  const unsigned short* __restrict__ csr,
                                                  const float* __restrict__ W2,
                                                  unsigned short* __restrict__ Yout, int n) {
    __shared__ float Ws[64 * 64];   // 16 KB
    __shared__ float hs[4][64];     // 1 KB
    const ushort4* Y4 = (const ushort4*)Y;
    int t = threadIdx.x, w = t >> 6, l = t & 63;
    int q = l >> 4, c = l & 15;
    int node = blockIdx.x * 4 + w;
    bool valid = node < n;
    // gather head: issue early (overlaps W2 staging below)
    int beg = 0, end = 0;
    float dv = 0.f;
    float4 acc = make_float4(0.f, 0.f, 0.f, 0.f);
    if (valid) {
        beg = offsets[node];
        end = offsets[node + 1];
        dv = dinv[node];
        if (q == 0) {
            ushort4 u = Y4[(size_t)node * 16 + c];
            acc = make_float4(bf2f(u.x), bf2f(u.y), bf2f(u.z), bf2f(u.w));
        }
    }
    beg = __builtin_amdgcn_readfirstlane(beg);  // wave-uniform -> SGPR
    end = __builtin_amdgcn_readfirstlane(end);
    {
        const float4* W4 = (const float4*)W2;
        float4* Ws4 = (float4*)Ws;
#pragma unroll
        for (int j = 0; j < 4; j++) Ws4[t + 256 * j] = W4[t + 256 * j];
    }
    if (valid) {
        for (int j = beg; j < end; j += 16) {
#pragma unroll
            for (int u = 0; u < 4; u++) {
                int jj = j + 4 * u + q;
                if (jj < end) {
                    int s = csr[jj];                     // slot-uniform -> bcast
                    ushort4 v = Y4[(size_t)s * 16 + c];  // 16 lanes x 8B = row
                    acc.x += bf2f(v.x); acc.y += bf2f(v.y);
                    acc.z += bf2f(v.z); acc.w += bf2f(v.w);
                }
            }
        }
#pragma unroll
        for (int m = 16; m <= 32; m <<= 1) {
            acc.x += __shfl_xor(acc.x, m);
            acc.y += __shfl_xor(acc.y, m);
            acc.z += __shfl_xor(acc.z, m);
            acc.w += __shfl_xor(acc.w, m);
        }
        float4 b4 = ((const float4*)bias)[c];
        acc.x = fmaxf(dv * acc.x + b4.x, 0.f);
        acc.y = fmaxf(dv * acc.y + b4.y, 0.f);
        acc.z = fmaxf(dv * acc.z + b4.z, 0.f);
        acc.w = fmaxf(dv * acc.w + b4.w, 0.f);
    }
    if (q == 0) ((float4*)hs[w])[c] = acc;  // zeros if invalid
    __syncthreads();
    if (valid) {
        float acc2 = 0.f;
#pragma unroll
        for (int m = 0; m < 16; m++) {
            float4 h4 = ((const float4*)hs[w])[m];   // wave-broadcast
            acc2 += h4.x * Ws[(4 * m + 0) * 64 + l] + h4.y * Ws[(4 * m + 1) * 64 + l]
                  + h4.z * Ws[(4 * m + 2) * 64 + l] + h4.w * Ws[(4 * m + 3) * 64 + l];
        }
        Yout[(size_t)node * 64 + l] = f2bf(dv * acc2);
    }
}

// Layer-2 aggregate + per-block partial mean rows (R12 structure, scalar
// gather bounds).
__global__ __launch_bounds__(256) void k_agg_pool(const unsigned short* __restrict__ Y,
                                                  const float* __restrict__ dinv,
                                                  const float* __restrict__ bias,
                                                  const int* __restrict__ offsets,
                                                  const unsigned short* __restrict__ csr,
                                                  float* __restrict__ pbuf, int n) {
    __shared__ float4 sm4[4][16];
    const ushort4* Y4 = (const ushort4*)Y;
    int t = threadIdx.x, w = t >> 6, l = t & 63;
    int q = l >> 4, c = l & 15;
    int node = blockIdx.x * 4 + w;
    bool valid = node < n;
    int beg = 0, end = 0;
    float dv = 0.f;
    float4 hval = make_float4(0.f, 0.f, 0.f, 0.f);
    float4 acc = make_float4(0.f, 0.f, 0.f, 0.f);
    if (valid) {
        beg = offsets[node];
        end = offsets[node + 1];
        dv = dinv[node];
        if (q == 0) {
            ushort4 u = Y4[(size_t)node * 16 + c];
            acc = make_float4(bf2f(u.x), bf2f(u.y), bf2f(u.z), bf2f(u.w));
        }
    }
    beg = __builtin_amdgcn_readfirstlane(beg);
    end = __builtin_amdgcn_readfirstlane(end);
    if (valid) {
        for (int j = beg; j < end; j += 16) {
#pragma unroll
            for (int u = 0; u < 4; u++) {
                int jj = j + 4 * u + q;
                if (jj < end) {
                    int s = csr[jj];
                    ushort4 v = Y4[(size_t)s * 16 + c];
                    acc.x += bf2f(v.x); acc.y += bf2f(v.y);
                    acc.z += bf2f(v.z); acc.w += bf2f(v.w);
                }
            }
        }
#pragma unroll
        for (int m = 16; m <= 32; m <<= 1) {
            acc.x += __shfl_xor(acc.x, m);
            acc.y += __shfl_xor(acc.y, m);
            acc.z += __shfl_xor(acc.z, m);
            acc.w += __shfl_xor(acc.w, m);
        }
        float4 b4 = ((const float4*)bias)[c];
        hval.x = fmaxf(dv * acc.x + b4.x, 0.f);
        hval.y = fmaxf(dv * acc.y + b4.y, 0.f);
        hval.z = fmaxf(dv * acc.z + b4.z, 0.f);
        hval.w = fmaxf(dv * acc.w + b4.w, 0.f);
    }
    if (q == 0) sm4[w][c] = valid ? hval : make_float4(0.f, 0.f, 0.f, 0.f);
    __syncthreads();
    if (t < 16) {
        float4 a = sm4[0][t], b = sm4[1][t], d = sm4[2][t], e = sm4[3][t];
        float4 s;
        s.x = (a.x + b.x) + (d.x + e.x);
        s.y = (a.y + b.y) + (d.y + e.y);
        s.z = (a.z + b.z) + (d.z + e.z);
        s.w = (a.w + b.w) + (d.w + e.w);
        ((float4*)pbuf)[(size_t)blockIdx.x * 16 + t] = s;
    }
}

__global__ void k_mean_final(const float* __restrict__ pbuf, float* __restrict__ g,
                             int nrows) {
    __shared__ float part[256];
    int t = threadIdx.x, w = t >> 6, f = t & 63;
    float local = 0.f;
    for (int r = blockIdx.x * 4 + w; r < nrows; r += gridDim.x * 4)
        local += pbuf[(size_t)r * 64 + f];
    part[t] = local;
    __syncthreads();
    if (w == 0) {
        float tot = part[f] + part[64 + f] + part[128 + f] + part[192 + f];
        atomicAdd(&g[f], tot);
    }
}

__global__ void k_readout(const float* __restrict__ g, const float* __restrict__ Wr,
                          const float* __restrict__ br, float* __restrict__ out,
                          float invn) {
    __shared__ float gl[64];
    int t = threadIdx.x;
    if (t < 64) gl[t] = g[t] * invn;
    __syncthreads();
    float acc = br[t];
#pragma unroll
    for (int k = 0; k < 64; k++) acc += gl[k] * Wr[k * 128 + t];
    out[t] = acc;
}

extern "C" void kernel_launch(void* const* d_in, const int* in_sizes, int n_in,
                              void* d_out, int out_size, void* d_ws, size_t ws_size,
                              hipStream_t stream) {
    const float* x  = (const float*)d_in[0];
    const int*   ei = (const int*)d_in[1];   // int32 on device (JAX x64 off)
    const float* W1 = (const float*)d_in[2];
    const float* b1 = (const float*)d_in[3];
    const float* W2 = (const float*)d_in[4];
    const float* b2 = (const float*)d_in[5];
    const float* Wr = (const float*)d_in[6];
    const float* br = (const float*)d_in[7];
    float* out = (float*)d_out;

    int n = in_sizes[0] / 64;   // 50000
    int E = in_sizes[1] / 2;    // 800000
    const int* src = ei;
    const int* dst = ei + E;

    int NB  = (n + 63) / 64;       // 782 buckets of 64 nodes
    int nch = (E + CH - 1) / CH;   // 196 chunks

    // workspace layout (~22 MB)
    char* p = (char*)d_ws;
    unsigned short* y1 = (unsigned short*)p; p += (size_t)n * 64 * sizeof(unsigned short);
    unsigned short* y2 = (unsigned short*)p; p += (size_t)n * 64 * sizeof(unsigned short);
    float* pbuf = (float*)p;   p += (size_t)((n + 3) / 4) * 64 * sizeof(float);
    float* dinv = (float*)p;   p += (size_t)n * sizeof(float);
    float* g = (float*)p;      p += 64 * sizeof(float);
    int* staged = (int*)p;     p += (size_t)E * sizeof(int);
    int* offsets = (int*)p;    p += (size_t)(n + 1) * sizeof(int);
    int* histmat = (int*)p;    p += (size_t)nch * NB * sizeof(int);
    int* bstart = (int*)p;     p += (size_t)(NB + 1) * sizeof(int);
    unsigned short* csr = (unsigned short*)p; p += (size_t)E * sizeof(unsigned short);

    k_bucket_hist<<<nch, 256, 0, stream>>>(dst, histmat, E, NB);
    k_scan<<<1, 1024, 0, stream>>>(histmat, bstart, offsets, g, NB, nch, E, n);
    k_bucket_scatter<<<nch, 256, 0, stream>>>(src, dst, histmat, bstart, staged, E, NB);
    k_local_sort<<<NB, 256, 0, stream>>>(staged, bstart, csr, offsets, dinv, n);

    int gb = (n + 3) / 4;  // 12500 aggregate blocks (one wave per node)
    k_gemm_scale<<<(n + 15) / 16, 256, 0, stream>>>(x, W1, dinv, y1, n);
    k_agg_fuse<<<gb, 256, 0, stream>>>(y1, dinv, b1, offsets, csr, W2, y2, n);
    k_agg_pool<<<gb, 256, 0, stream>>>(y2, dinv, b2, offsets, csr, pbuf, n);

    k_mean_final<<<64, 256, 0, stream>>>(pbuf, g, gb);
    k_readout<<<1, 128, 0, stream>>>(g, Wr, br, out, 1.0f / (float)n);
}